// Round 7
// baseline (47.503 us; speedup 1.0000x reference)
//
#include <hip/hip_runtime.h>

// RDF loss: all-pairs distance histogram (10 unit bins) -> rdf -> MSE.
// i-register blocking: each lane owns IBLK=4 i-points, so one broadcast
// ds_read_b128 (j-point from LDS) feeds 4 pair computations (round-6
// bottleneck was 1 LDS read per pair on the shared per-CU LDS pipe).
// Grid: x = i-tile (1024 pts), y = j-chunk (64 pts); valid iff chunk has
// some j > i_min (rect-pruned triangle); straddling chunks mask j>i per
// pair (template). Pair math: Gram-form d2 (coords pre-scaled 1/dr) ->
// v_sqrt -> v_cvt_u32 (sat, NaN->0) -> min(b,10) -> u64 packed counter
// (10 fields x 6 bits, flush every 8 j's: 32 adds max per field).
// Non-atomic per-block partials; fused reduce+loss. Reference emulation:
// fp32 segment_sum saturates at 2^24 -> clamp per bin.

#define BLOCK    256
#define IBLK     4
#define ITILE    (BLOCK * IBLK)   // 1024
#define JCH      64
#define NB       10
#define SLOT     16               // u32 stride between block-partial rows
#define FP32_SAT 16777216u        // 2^24

template <bool STRADDLE>
__device__ __forceinline__ void jloop(const float4* __restrict__ sj,
                                      const float* sqi, const float* m2x,
                                      const float* m2y, const float* m2z,
                                      const int* iidx, int jbase,
                                      unsigned int* c)
{
    for (int jc = 0; jc < JCH; jc += 8) {
        unsigned long long cnt = 0ull;
        #pragma unroll
        for (int jj = 0; jj < 8; ++jj) {
            const int j = jc + jj;
            float4 p = sj[j];
            #pragma unroll
            for (int r = 0; r < IBLK; ++r) {
                float d2 = sqi[r] + p.w;
                d2 = fmaf(m2x[r], p.x, d2);
                d2 = fmaf(m2y[r], p.y, d2);
                d2 = fmaf(m2z[r], p.z, d2);
                if (STRADDLE) d2 = (jbase + j > iidx[r]) ? d2 : 3.0e30f;
                float d = __builtin_amdgcn_sqrtf(d2);
                unsigned int b = (unsigned int)d;   // v_cvt_u32_f32: sat, NaN->0
                b = min(b, 10u);                    // 10 = trash field (bits 60+)
                cnt += 1ull << (b * 6u);
            }
        }
        #pragma unroll
        for (int k = 0; k < NB; ++k)
            c[k] += (unsigned int)(cnt >> (6 * k)) & 63u;
    }
}

__global__ __launch_bounds__(BLOCK) void rdf_hist_kernel(
    const float* __restrict__ pc, const int* __restrict__ rmaxp,
    const float* __restrict__ drp, unsigned int* __restrict__ part, int n)
{
    const int I  = (int)blockIdx.x;       // i-tile of ITILE points
    const int Jc = (int)blockIdx.y;       // j-chunk of JCH points
    const int jbase = Jc * JCH;
    const int ibase = I * ITILE;
    if (jbase + JCH - 1 <= ibase) return;           // entirely at/below diagonal

    __shared__ float4 sj[JCH];
    __shared__ unsigned int sacc[NB];

    const int tid = threadIdx.x;
    const float inv_dr = 1.0f / (*drp);

    if (tid < NB) sacc[tid] = 0u;
    if (tid < JCH) {
        const int j = jbase + tid;
        float x = -3.0e4f, y = -3.0e4f, z = -3.0e4f;   // j-pad sentinel
        if (j < n) { x = pc[3*j] * inv_dr; y = pc[3*j+1] * inv_dr; z = pc[3*j+2] * inv_dr; }
        sj[tid] = make_float4(x, y, z, x*x + y*y + z*z);
    }

    float sqi[IBLK], m2x[IBLK], m2y[IBLK], m2z[IBLK];
    int iidx[IBLK];
    #pragma unroll
    for (int r = 0; r < IBLK; ++r) {
        const int i = ibase + tid + BLOCK * r;
        iidx[r] = i;
        float x = 3.0e4f, y = 3.0e4f, z = 3.0e4f;      // i-pad: opposite sign
        if (i < n) { x = pc[3*i] * inv_dr; y = pc[3*i+1] * inv_dr; z = pc[3*i+2] * inv_dr; }
        sqi[r] = x*x + y*y + z*z;
        m2x[r] = -2.f * x; m2y[r] = -2.f * y; m2z[r] = -2.f * z;
    }

    __syncthreads();

    unsigned int c[NB];
    #pragma unroll
    for (int k = 0; k < NB; ++k) c[k] = 0u;

    if (jbase <= ibase + ITILE - 1)                 // chunk straddles diagonal
        jloop<true >(sj, sqi, m2x, m2y, m2z, iidx, jbase, c);
    else
        jloop<false>(sj, sqi, m2x, m2y, m2z, iidx, jbase, c);

    // wave butterfly -> LDS combine -> one non-atomic partial row per block
    #pragma unroll
    for (int k = 0; k < NB; ++k) {
        unsigned int s = c[k];
        #pragma unroll
        for (int m = 32; m >= 1; m >>= 1) s += (unsigned int)__shfl_xor((int)s, m, 64);
        c[k] = s;
    }
    if ((tid & 63) == 0) {
        #pragma unroll
        for (int k = 0; k < NB; ++k) atomicAdd(&sacc[k], c[k]);
    }
    __syncthreads();
    const int bid = (int)blockIdx.x + (int)gridDim.x * (int)blockIdx.y;
    if (tid < NB) part[bid * SLOT + tid] = sacc[tid];
}

__global__ __launch_bounds__(BLOCK) void rdf_reduce_loss_kernel(
    const unsigned int* __restrict__ part, const float* __restrict__ target,
    const int* __restrict__ rmaxp, const float* __restrict__ drp,
    float* __restrict__ out, int n, int mt, int nI, int nJ)
{
    __shared__ unsigned int sacc[NB];
    const int tid = threadIdx.x;
    if (tid < NB) sacc[tid] = 0u;
    __syncthreads();

    unsigned int a[NB];
    #pragma unroll
    for (int k = 0; k < NB; ++k) a[k] = 0u;
    const int nslots = nI * nJ;
    for (int s = tid; s < nslots; s += BLOCK) {
        const int I  = s % nI;
        const int Jc = s / nI;
        if (Jc * JCH + JCH - 1 > I * ITILE) {       // only valid (written) slots
            #pragma unroll
            for (int k = 0; k < NB; ++k) a[k] += part[s * SLOT + k];
        }
    }
    #pragma unroll
    for (int k = 0; k < NB; ++k) {
        unsigned int s = a[k];
        #pragma unroll
        for (int m = 32; m >= 1; m >>= 1) s += (unsigned int)__shfl_xor((int)s, m, 64);
        if ((tid & 63) == 0) atomicAdd(&sacc[k], s);
    }
    __syncthreads();

    if (tid == 0) {
        const float PI = 3.14159265358979323846f;
        const float rmax = (float)(*rmaxp);
        const float dr   = *drp;
        int nbins = (int)roundf(rmax / dr);
        if (nbins > NB) nbins = NB;
        const float density = (float)n / (4.0f / 3.0f * PI * rmax * rmax * rmax);
        const int m = (mt < nbins) ? mt : nbins;
        float acc = 0.0f;
        for (int b = 0; b < m; ++b) {
            unsigned int hb = 2u * sacc[b] + ((b == 0) ? (unsigned int)n : 0u);
            if (hb > FP32_SAT) hb = FP32_SAT;   // fp32 segment_sum saturation
            float r_mid = ((float)b + 0.5f) * dr;
            float ideal = 4.0f * PI * r_mid * r_mid * dr * density * (float)n;
            float rdf  = (ideal != 0.0f) ? ((float)hb / ideal) : 0.0f;
            float diff = rdf - target[b];
            acc = fmaf(diff, diff, acc);
        }
        out[0] = acc / (float)m;
    }
}

extern "C" void kernel_launch(void* const* d_in, const int* in_sizes, int n_in,
                              void* d_out, int out_size, void* d_ws, size_t ws_size,
                              hipStream_t stream)
{
    const float* pc     = (const float*)d_in[0];
    const float* target = (const float*)d_in[1];
    const int*   rmaxp  = (const int*)d_in[2];
    const float* drp    = (const float*)d_in[3];
    const int n  = in_sizes[0] / 3;
    const int mt = in_sizes[1];

    unsigned int* part = (unsigned int*)d_ws;
    const int nI = (n + ITILE - 1) / ITILE;
    const int nJ = (n + JCH - 1) / JCH;

    dim3 grid(nI, nJ);
    rdf_hist_kernel<<<grid, BLOCK, 0, stream>>>(pc, rmaxp, drp, part, n);
    rdf_reduce_loss_kernel<<<1, BLOCK, 0, stream>>>(part, target, rmaxp, drp,
                                                    (float*)d_out, n, mt, nI, nJ);
}

// Round 8
// 41.610 us; speedup vs baseline: 1.1416x; 1.1416x over previous
//
#include <hip/hip_runtime.h>

// RDF loss: all-pairs distance histogram (10 unit bins) -> rdf -> MSE.
// Dense triangular grid: exactly the live (i-tile=1024, j-chunk=64) blocks,
// bid -> (k, jc) via quadratic decode + fixup. No dead blocks, uniform work
// (round-7 bottleneck: 46% dead blocks + exposed prologue -> occupancy 24%).
// IBLK=4: each lane owns 4 i-points; one broadcast ds_read_b128 per j feeds
// 4 pair computations. Issue-early staging: all raw global loads issued
// before first use (single latency drain). Pair math: Gram-form d2 (coords
// pre-scaled 1/dr) -> v_sqrt -> v_cvt_u32 (sat, NaN->0) -> min(b,10) ->
// u64 packed counter (10 fields x 6 bits, flushed every 8 j's = 32 adds max).
// Non-atomic per-block partials; fused reduce+loss kernel.
// Reference emulation: fp32 segment_sum saturates at 2^24 -> clamp per bin.

#define BLOCK    256
#define IBLK     4
#define ITILE    (BLOCK * IBLK)   // 1024
#define JCH      64
#define DJC      (ITILE / JCH)    // 16 j-chunks per i-tile
#define NB       10
#define SLOT     16               // u32 stride between block-partial rows
#define FP32_SAT 16777216u        // 2^24

__device__ __forceinline__ int pre_rows(int k, int njc) {
    // number of blocks before i-tile k: sum_{m<k} (njc - DJC*m)
    return k * njc - (DJC / 2) * k * (k - 1);
}

template <bool STRADDLE>
__device__ __forceinline__ void jloop(const float4* __restrict__ sj,
                                      const float* sqi, const float* m2x,
                                      const float* m2y, const float* m2z,
                                      const int* iidx, int jbase,
                                      unsigned int* c)
{
    for (int jc0 = 0; jc0 < JCH; jc0 += 8) {
        unsigned long long cnt = 0ull;
        #pragma unroll
        for (int jj = 0; jj < 8; ++jj) {
            const int j = jc0 + jj;
            float4 p = sj[j];
            #pragma unroll
            for (int r = 0; r < IBLK; ++r) {
                float d2 = sqi[r] + p.w;
                d2 = fmaf(m2x[r], p.x, d2);
                d2 = fmaf(m2y[r], p.y, d2);
                d2 = fmaf(m2z[r], p.z, d2);
                if (STRADDLE) d2 = (jbase + j > iidx[r]) ? d2 : 3.0e30f;
                float d = __builtin_amdgcn_sqrtf(d2);
                unsigned int b = (unsigned int)d;   // v_cvt_u32_f32: sat, NaN->0
                b = min(b, 10u);                    // 10 = trash field (bits 60+)
                cnt += 1ull << (b * 6u);
            }
        }
        #pragma unroll
        for (int k = 0; k < NB; ++k)
            c[k] += (unsigned int)(cnt >> (6 * k)) & 63u;
    }
}

__global__ __launch_bounds__(BLOCK) void rdf_hist_kernel(
    const float* __restrict__ pc, const int* __restrict__ rmaxp,
    const float* __restrict__ drp, unsigned int* __restrict__ part,
    int n, int nI, int njc)
{
    __shared__ float4 sj[JCH];
    __shared__ unsigned int sacc[NB];

    const int tid = threadIdx.x;
    const int bid = (int)blockIdx.x;

    // decode dense triangular work index -> (i-tile k, j-chunk jc)
    const float a  = (float)(DJC / 2);                     // 8
    const float bq = (float)njc + a;
    float disc = bq * bq - 4.0f * a * (float)bid;
    disc = fmaxf(disc, 0.0f);
    int k = (int)((bq - sqrtf(disc)) / (2.0f * a));
    k = max(0, min(k, nI - 1));
    while (k > 0 && pre_rows(k, njc) > bid) --k;
    while (k + 1 < nI && pre_rows(k + 1, njc) <= bid) ++k;
    const int jc    = (bid - pre_rows(k, njc)) + DJC * k;  // >= diagonal chunk
    const int ibase = k * ITILE;
    const int jbase = jc * JCH;

    // scalar param (everything scales by 1/dr)
    const float inv_dr = 1.0f / (*drp);

    // ---- issue ALL raw global loads before first use (one latency drain) ----
    float jx = -3.0e4f, jy = -3.0e4f, jz = -3.0e4f;        // j-pad sentinel
    if (tid < JCH) {
        const int j = jbase + tid;
        if (j < n) { jx = pc[3*j]; jy = pc[3*j+1]; jz = pc[3*j+2]; }
    }
    float rx[IBLK], ry[IBLK], rz[IBLK];
    int iidx[IBLK];
    #pragma unroll
    for (int r = 0; r < IBLK; ++r) {
        const int i = ibase + tid + BLOCK * r;
        iidx[r] = i;
        rx[r] = 3.0e4f; ry[r] = 3.0e4f; rz[r] = 3.0e4f;    // i-pad: opposite sign
        if (i < n) { rx[r] = pc[3*i]; ry[r] = pc[3*i+1]; rz[r] = pc[3*i+2]; }
    }

    if (tid < NB) sacc[tid] = 0u;
    if (tid < JCH) {
        const float x = jx * inv_dr, y = jy * inv_dr, z = jz * inv_dr;
        sj[tid] = make_float4(x, y, z, x*x + y*y + z*z);
    }
    float sqi[IBLK], m2x[IBLK], m2y[IBLK], m2z[IBLK];
    #pragma unroll
    for (int r = 0; r < IBLK; ++r) {
        const float x = rx[r] * inv_dr, y = ry[r] * inv_dr, z = rz[r] * inv_dr;
        sqi[r] = x*x + y*y + z*z;
        m2x[r] = -2.f * x; m2y[r] = -2.f * y; m2z[r] = -2.f * z;
    }

    __syncthreads();

    unsigned int c[NB];
    #pragma unroll
    for (int q = 0; q < NB; ++q) c[q] = 0u;

    if (jbase < ibase + ITILE)                  // chunk straddles diagonal band
        jloop<true >(sj, sqi, m2x, m2y, m2z, iidx, jbase, c);
    else
        jloop<false>(sj, sqi, m2x, m2y, m2z, iidx, jbase, c);

    // wave butterfly -> LDS combine -> one non-atomic partial row per block
    #pragma unroll
    for (int q = 0; q < NB; ++q) {
        unsigned int s = c[q];
        #pragma unroll
        for (int m = 32; m >= 1; m >>= 1) s += (unsigned int)__shfl_xor((int)s, m, 64);
        c[q] = s;
    }
    if ((tid & 63) == 0) {
        #pragma unroll
        for (int q = 0; q < NB; ++q) atomicAdd(&sacc[q], c[q]);
    }
    __syncthreads();
    if (tid < NB) part[bid * SLOT + tid] = sacc[tid];
}

__global__ __launch_bounds__(BLOCK) void rdf_reduce_loss_kernel(
    const unsigned int* __restrict__ part, const float* __restrict__ target,
    const int* __restrict__ rmaxp, const float* __restrict__ drp,
    float* __restrict__ out, int n, int mt, int nblocks)
{
    __shared__ unsigned int sacc[NB];
    const int tid = threadIdx.x;
    if (tid < NB) sacc[tid] = 0u;
    __syncthreads();

    unsigned int a[NB];
    #pragma unroll
    for (int q = 0; q < NB; ++q) a[q] = 0u;
    for (int s = tid; s < nblocks; s += BLOCK) {
        #pragma unroll
        for (int q = 0; q < NB; ++q) a[q] += part[s * SLOT + q];
    }
    #pragma unroll
    for (int q = 0; q < NB; ++q) {
        unsigned int s = a[q];
        #pragma unroll
        for (int m = 32; m >= 1; m >>= 1) s += (unsigned int)__shfl_xor((int)s, m, 64);
        if ((tid & 63) == 0) atomicAdd(&sacc[q], s);
    }
    __syncthreads();

    if (tid == 0) {
        const float PI = 3.14159265358979323846f;
        const float rmax = (float)(*rmaxp);
        const float dr   = *drp;
        int nbins = (int)roundf(rmax / dr);
        if (nbins > NB) nbins = NB;
        const float density = (float)n / (4.0f / 3.0f * PI * rmax * rmax * rmax);
        const int m = (mt < nbins) ? mt : nbins;
        float acc = 0.0f;
        for (int b = 0; b < m; ++b) {
            unsigned int hb = 2u * sacc[b] + ((b == 0) ? (unsigned int)n : 0u);
            if (hb > FP32_SAT) hb = FP32_SAT;   // fp32 segment_sum saturation
            float r_mid = ((float)b + 0.5f) * dr;
            float ideal = 4.0f * PI * r_mid * r_mid * dr * density * (float)n;
            float rdf  = (ideal != 0.0f) ? ((float)hb / ideal) : 0.0f;
            float diff = rdf - target[b];
            acc = fmaf(diff, diff, acc);
        }
        out[0] = acc / (float)m;
    }
}

extern "C" void kernel_launch(void* const* d_in, const int* in_sizes, int n_in,
                              void* d_out, int out_size, void* d_ws, size_t ws_size,
                              hipStream_t stream)
{
    const float* pc     = (const float*)d_in[0];
    const float* target = (const float*)d_in[1];
    const int*   rmaxp  = (const int*)d_in[2];
    const float* drp    = (const float*)d_in[3];
    const int n  = in_sizes[0] / 3;
    const int mt = in_sizes[1];

    unsigned int* part = (unsigned int*)d_ws;
    const int nI  = (n + ITILE - 1) / ITILE;
    const int njc = (n + JCH - 1) / JCH;
    // dense triangular block count: sum_{k=0..nI-1} (njc - DJC*k)
    const int nblocks = nI * njc - (DJC / 2) * nI * (nI - 1);

    rdf_hist_kernel<<<nblocks, BLOCK, 0, stream>>>(pc, rmaxp, drp, part, n, nI, njc);
    rdf_reduce_loss_kernel<<<1, BLOCK, 0, stream>>>(part, target, rmaxp, drp,
                                                    (float*)d_out, n, mt, nblocks);
}